// Round 3
// baseline (18883.557 us; speedup 1.0000x reference)
//
#include <hip/hip_runtime.h>

// ---------------------------------------------------------------------------
// LSTM B=32, S=2048, E=512, H=512 (gates 4H=2048), fp32 in/out.
//   prep_kernel : permuted bias, zero tagged-h regions, lengths->floats.
//   xproj_gemm  : xp[t][b][n''] bf16 = x @ W_ih^T + bias (split-bf16 MFMA).
//   lstm_rec    : persistent 64 working WGs (2 clubs x 32), WG = 16 units x
//                 16 batches, W_hh in VGPRs (hi/lo split, 3-term MFMA).
//
//   R7: FAIL-SAFE XCD-CLUSTERED EXCHANGE.
//   Theory: R4/R5 both ~8000 cy/step because agent-scope ops are serviced at
//   the cross-XCD coherence point (LLC), ~2.5k cy RT. Fix = keep each club's
//   h-exchange inside ONE XCD's shared L2. R6 (roster+sc0 asm) died without
//   diagnostics, so R7 makes every assumption fail-SOFT:
//     * tag-in-data 8B entries {tag | packed h}: stale lines carry old tags
//       (tags strictly increase) -> fast path can never accept wrong data.
//     * dual-publish: FAST region (plain store -> local L2, write-through
//       L1) AND SLOW region (__hip_atomic_store AGENT -> LLC; R4/R5-verified).
//     * clustering via dispatch heuristic: grid=256 + 87KB LDS pad -> exactly
//       1 WG/CU -> block i on CU i, XCD = i%8 (documented round-robin).
//       club0 = blocks ==0 (mod 8) -> XCD0; club1 = ==1 (mod 8) -> XCD1.
//     * fast loads = __builtin_nontemporal_load (no L1 allocate, L2-served),
//       compiler-tracked; spin re-load forced by "memory" clobber; spin is
//       BOUNDED (256 iters) then sticky-falls-back to the SLOW agent-atomic
//       protocol (exactly R5's verified path). Wrong heuristic / nt / L2
//       model => fallback => R5 perf, still correct. No hang possible.
//   MFMA structure, LDS swizzle, K-permutation, gate math: R5-exact
//   (verified passing, absmax 0.00390625).
// ---------------------------------------------------------------------------

typedef __attribute__((ext_vector_type(8))) __bf16 bf16x8;
typedef __attribute__((ext_vector_type(8))) short short8;
typedef __attribute__((ext_vector_type(4))) float floatx4;
typedef __attribute__((ext_vector_type(2))) unsigned uint32x2;
typedef __attribute__((ext_vector_type(4))) unsigned uint32x4;

// ws layout (bytes)
#define XP_OFF     0ull
#define XP_BYTES   (2048ull * 32ull * 2048ull * 2ull)   // 268,435,456
#define FAST_OFF   (XP_OFF + XP_BYTES)    // [2][512 units][32 batches] x 8B
#define FAST_BYTES (2ull * 512ull * 32ull * 8ull)       // 262,144
#define SLOW_OFF   (FAST_OFF + FAST_BYTES)  // [2][32 batches][512 units] x 8B
#define SLOW_BYTES (2ull * 32ull * 512ull * 8ull)       // 262,144
#define BIAS_OFF   (SLOW_OFF + SLOW_BYTES)
#define WS_NEED    (BIAS_OFF + 8192ull)

// d_out layout (fp32): out[32][2048][1][512], lengths[32], hidden[1][32][512]
#define LEN_OFF_F    33554432
#define HIDDEN_OFF_F 33554464

__device__ inline float sigm(float x) { return 1.f / (1.f + __expf(-x)); }
__device__ inline float tanh_(float x) {
  float e = __expf(-2.f * fabsf(x));
  float r = (1.f - e) / (1.f + e);
  return x >= 0.f ? r : -r;
}

__device__ inline void cvt_hilo8(const float* v, bf16x8& hi, bf16x8& lo) {
#pragma unroll
  for (int i = 0; i < 8; ++i) {
    __bf16 h = (__bf16)v[i];
    hi[i] = h;
    lo[i] = (__bf16)(v[i] - (float)h);
  }
}

__device__ inline float bf16f(unsigned short u) {
  union { unsigned u; float f; } c; c.u = ((unsigned)u) << 16; return c.f;
}

// ---------------------------------------------------------------------------
__global__ __launch_bounds__(256) void prep_kernel(
    const float* __restrict__ bih, const float* __restrict__ bhh,
    const int* __restrict__ len, float* __restrict__ biasp,
    unsigned long long* __restrict__ hreg,  // FAST followed by SLOW
    float* __restrict__ outf) {
  const int gtid = blockIdx.x * 256 + threadIdx.x;
  if (gtid < 2048) {
    // n'' = ug4*16 + ul*4 + g  ->  W row = g*512 + ug4*4 + ul
    int i = gtid;
    int rowg = (i & 3) * 512 + (i >> 4) * 4 + ((i >> 2) & 3);
    biasp[i] = bih[rowg] + bhh[rowg];
  }
  // tag 0 == "h input for step 0" with payload 0 (h0 = 0). Odd-step buffers
  // read tag 0 as "not ready".
  for (int i = gtid; i < 65536; i += 16384) hreg[i] = 0ull;
  if (gtid < 32) outf[LEN_OFF_F + gtid] = (float)len[gtid];
}

// ---------------------------------------------------------------------------
// xp GEMM: M=65536 (b*2048+s), N=2048 (n''), K=512. Tile 64x64, BK=32.
__global__ __launch_bounds__(256) void xproj_gemm(
    const float* __restrict__ x, const float* __restrict__ Wih,
    const float* __restrict__ biasp, __bf16* __restrict__ xp) {
  __shared__ short Ash[64 * 40], Asl[64 * 40], Bsh[64 * 40], Bsl[64 * 40];
  const int tid = threadIdx.x;
  const int w = tid >> 6, lane = tid & 63, ln = lane & 15, kq = lane >> 4;
  const int ntile = blockIdx.x & 31, mtile = blockIdx.x >> 5;
  const int srow = tid >> 2, sseg = tid & 3;

  const size_t a_base = (size_t)(mtile * 64 + srow) * 512 + sseg * 8;
  const int np_s = ntile * 64 + srow;
  const int rowg = (np_s & 3) * 512 + (np_s >> 4) * 4 + ((np_s >> 2) & 3);
  const size_t b_base = (size_t)rowg * 512 + sseg * 8;

  floatx4 acc[4] = {{0,0,0,0},{0,0,0,0},{0,0,0,0},{0,0,0,0}};

  for (int k0 = 0; k0 < 512; k0 += 32) {
    floatx4 a0 = *(const floatx4*)(x + a_base + k0);
    floatx4 a1 = *(const floatx4*)(x + a_base + k0 + 4);
    floatx4 b0 = *(const floatx4*)(Wih + b_base + k0);
    floatx4 b1 = *(const floatx4*)(Wih + b_base + k0 + 4);
    __syncthreads();
    {
      float va[8] = {a0[0],a0[1],a0[2],a0[3],a1[0],a1[1],a1[2],a1[3]};
      bf16x8 hi, lo; cvt_hilo8(va, hi, lo);
      *(short8*)&Ash[srow * 40 + sseg * 8] = __builtin_bit_cast(short8, hi);
      *(short8*)&Asl[srow * 40 + sseg * 8] = __builtin_bit_cast(short8, lo);
      float vb[8] = {b0[0],b0[1],b0[2],b0[3],b1[0],b1[1],b1[2],b1[3]};
      cvt_hilo8(vb, hi, lo);
      *(short8*)&Bsh[srow * 40 + sseg * 8] = __builtin_bit_cast(short8, hi);
      *(short8*)&Bsl[srow * 40 + sseg * 8] = __builtin_bit_cast(short8, lo);
    }
    __syncthreads();
    bf16x8 ah = __builtin_bit_cast(bf16x8, *(const short8*)&Ash[(16 * w + ln) * 40 + kq * 8]);
    bf16x8 al = __builtin_bit_cast(bf16x8, *(const short8*)&Asl[(16 * w + ln) * 40 + kq * 8]);
#pragma unroll
    for (int nt = 0; nt < 4; ++nt) {
      bf16x8 bh = __builtin_bit_cast(bf16x8, *(const short8*)&Bsh[(nt * 16 + ln) * 40 + kq * 8]);
      bf16x8 bl = __builtin_bit_cast(bf16x8, *(const short8*)&Bsl[(nt * 16 + ln) * 40 + kq * 8]);
      acc[nt] = __builtin_amdgcn_mfma_f32_16x16x32_bf16(ah, bh, acc[nt], 0, 0, 0);
      acc[nt] = __builtin_amdgcn_mfma_f32_16x16x32_bf16(al, bh, acc[nt], 0, 0, 0);
      acc[nt] = __builtin_amdgcn_mfma_f32_16x16x32_bf16(ah, bl, acc[nt], 0, 0, 0);
    }
  }
#pragma unroll
  for (int nt = 0; nt < 4; ++nt) {
    const int npg = ntile * 64 + nt * 16 + ln;
    const float bs = biasp[npg];
#pragma unroll
    for (int r = 0; r < 4; ++r) {
      const int m = mtile * 64 + w * 16 + kq * 4 + r;
      const int s = m & 2047, b = m >> 11;
      xp[(size_t)(s * 32 + b) * 2048 + npg] = (__bf16)(acc[nt][r] + bs);
    }
  }
}

// ---------------------------------------------------------------------------
__global__ __launch_bounds__(256, 1) void lstm_rec(
    const float* __restrict__ Whh, const int* __restrict__ lengths,
    const __bf16* __restrict__ xp, float* __restrict__ out,
    float* __restrict__ hid, unsigned long long* __restrict__ fastR,
    unsigned long long* __restrict__ slowR) {
  __shared__ short Hh[16 * 512];       // [m][K-pos] bf16 hi, xor-swizzled
  __shared__ short Hl[16 * 512];
  __shared__ float Part[4 * 1088];     // [wave][nt(272 pad)][m][n]
  __shared__ volatile char ldspad[36864];  // occupancy throttle -> 1 WG/CU

  const int blk = blockIdx.x;
  const int bh = blk & 7;              // dispatch-heuristic XCD id
  const int ug = blk >> 3;             // 16-unit group within club
  if (bh >= 2 || ug >= 32) return;     // 192 of 256 blocks: exit immediately

  const int tid = threadIdx.x;
  if (tid == 0) ldspad[0] = 1;         // keep the pad allocated

  const int w = tid >> 6, lane = tid & 63, ln = lane & 15, kq = lane >> 4;
  const int b0 = bh * 16;

  // Persistent W_hh frags with the R5 K-permutation: K-pos 2j <- unit j,
  // K-pos 2j+1 <- unit j+256 (consumer thread tid owns units {tid, tid+256}
  // = contiguous K-positions {2tid, 2tid+1}).
  // Tile nt, lane ln: g=ln&3, ul=ln>>2, unit = ug*16+nt*4+ul, row=g*512+unit.
  bf16x8 whi[4][4], wlo[4][4];
#pragma unroll
  for (int nt = 0; nt < 4; ++nt) {
    const int rowg = (ln & 3) * 512 + (ug * 4 + nt) * 4 + (ln >> 2);
#pragma unroll
    for (int kc = 0; kc < 4; ++kc) {
      const int h0 = w * 64 + kc * 16 + kq * 4;  // (w*128+kc*32+kq*8)/2
      floatx4 f0 = *(const floatx4*)(Whh + (size_t)rowg * 512 + h0);
      floatx4 f1 = *(const floatx4*)(Whh + (size_t)rowg * 512 + h0 + 256);
      float v[8] = {f0[0],f1[0],f0[1],f1[1],f0[2],f1[2],f0[3],f1[3]};
      cvt_hilo8(v, whi[nt][kc], wlo[nt][kc]);
    }
  }

  // Elementwise ownership: 1 (batch,unit) per thread.
  const int m_e = tid >> 4, ue = tid & 15;
  const int b_e = b0 + m_e, u_e = ug * 16 + ue;
  const int lenb = lengths[b_e];
  float cst = 0.f, hcap = 0.f;

  // xp: this thread's 4 gate pre-acts are 8B contiguous (plain cached loads).
  const __bf16* xpb = xp + (size_t)b_e * 2048 + ug * 64 + (ue >> 2) * 16 + (ue & 3) * 4;
  uint32x2 xpcur = *(const uint32x2*)xpb;  // t = 0
  uint32x2 xpnext;

  // FAST region [buf][unit][batch]: thread's 32 entries = 2 x 128B runs.
  const char* Fb = (const char*)fastR;
  // publish addresses
  char* fpub_base = (char*)fastR + ((size_t)u_e * 32 + b_e) * 8;
  unsigned long long* spub_base = slowR + (size_t)b_e * 512 + u_e;

  int fastmode = 1;

  for (int t = 0; t < 2048; ++t) {
    // xp prefetch for t+1 (in flight across the exchange + MFMA phases)
    {
      const int tn = (t + 1 < 2048) ? t + 1 : 2047;
      xpnext = *(const uint32x2*)(xpb + (size_t)tn * 65536);
    }
    // ---- stage h: FAST path = nt loads from the club's shared L2, tags
    // travel with data; bounded spin; sticky fallback to SLOW (LLC). ----
    unsigned pk0[16], pk1[16];  // payloads: unit tid / unit tid+256, batch k
    uint32x4 q[16];
    if (fastmode) {
      const uint32x4* fb0 = (const uint32x4*)(Fb + (size_t)(t & 1) * 131072 +
                                              (size_t)tid * 256 + (size_t)b0 * 8);
      const uint32x4* fb1 = (const uint32x4*)((const char*)fb0 + 65536);
      int spins = 0;
      for (;;) {
        bool ok = true;
#pragma unroll
        for (int j = 0; j < 8; ++j) {
          q[j] = __builtin_nontemporal_load(fb0 + j);
          q[8 + j] = __builtin_nontemporal_load(fb1 + j);
        }
#pragma unroll
        for (int j = 0; j < 16; ++j)
          ok = ok && (q[j][1] == (unsigned)t) && (q[j][3] == (unsigned)t);
        if (ok) break;
        if (++spins > 256) { fastmode = 0; break; }  // sticky fallback
        __builtin_amdgcn_s_sleep(2);
        asm volatile("" ::: "memory");  // force re-load next iteration
      }
    }
    if (fastmode) {
#pragma unroll
      for (int j = 0; j < 8; ++j) {
        pk0[2 * j] = q[j][0];
        pk0[2 * j + 1] = q[j][2];
        pk1[2 * j] = q[8 + j][0];
        pk1[2 * j + 1] = q[8 + j][2];
      }
    } else {
      // SLOW: R5-verified agent-scope protocol on the mirror region.
      const unsigned long long* sb = slowR + (size_t)(t & 1) * 16384 + b0 * 512;
      unsigned long long e[32];
      for (;;) {
        bool ok = true;
#pragma unroll
        for (int k = 0; k < 16; ++k) {
          e[2 * k] = __hip_atomic_load(sb + (size_t)k * 512 + tid,
                                       __ATOMIC_RELAXED, __HIP_MEMORY_SCOPE_AGENT);
          e[2 * k + 1] = __hip_atomic_load(sb + (size_t)k * 512 + tid + 256,
                                           __ATOMIC_RELAXED, __HIP_MEMORY_SCOPE_AGENT);
        }
#pragma unroll
        for (int k = 0; k < 32; ++k)
          ok = ok && ((unsigned)(e[k] >> 32) == (unsigned)t);
        if (ok) break;
        __builtin_amdgcn_s_sleep(4);
      }
#pragma unroll
      for (int k = 0; k < 16; ++k) {
        pk0[k] = (unsigned)e[2 * k];
        pk1[k] = (unsigned)e[2 * k + 1];
      }
    }
    // ---- unpack hi/lo -> swizzled LDS planes (R5-exact combine) ----
    {
      const int g = tid >> 2;  // granule of 8 K-positions
#pragma unroll
      for (int k = 0; k < 16; ++k) {
        const unsigned d0 = pk0[k], d1 = pk1[k];
        const int d = k * 512 + ((g ^ (k & 7)) * 8) + (tid & 3) * 2;
        *(unsigned*)&Hh[d] = (d0 >> 16) | (d1 & 0xffff0000u);
        *(unsigned*)&Hl[d] = (d0 & 0xffffu) | (d1 << 16);
      }
    }
    __syncthreads();
    // ---- MFMA: M=16 batches x N=16 gate-rows x 4 tiles, wave K-slice ----
    floatx4 acc[4] = {{0,0,0,0},{0,0,0,0},{0,0,0,0},{0,0,0,0}};
#pragma unroll
    for (int kc = 0; kc < 4; ++kc) {
      const int g = w * 16 + kc * 4 + kq;
      const int d = ln * 512 + ((g ^ (ln & 7)) * 8);
      bf16x8 ah = __builtin_bit_cast(bf16x8, *(const short8*)&Hh[d]);
      bf16x8 al = __builtin_bit_cast(bf16x8, *(const short8*)&Hl[d]);
#pragma unroll
      for (int nt = 0; nt < 4; ++nt) {
        acc[nt] = __builtin_amdgcn_mfma_f32_16x16x32_bf16(ah, whi[nt][kc], acc[nt], 0, 0, 0);
        acc[nt] = __builtin_amdgcn_mfma_f32_16x16x32_bf16(al, whi[nt][kc], acc[nt], 0, 0, 0);
        acc[nt] = __builtin_amdgcn_mfma_f32_16x16x32_bf16(ah, wlo[nt][kc], acc[nt], 0, 0, 0);
      }
    }
#pragma unroll
    for (int nt = 0; nt < 4; ++nt)
#pragma unroll
      for (int r4 = 0; r4 < 4; ++r4)
        Part[w * 1088 + nt * 272 + (kq * 4 + r4) * 16 + ln] = acc[nt][r4];
    __syncthreads();
    // ---- reduce + gates + state (all 256 threads, one (b,u) each) ----
    {
      const int pb = (ue >> 2) * 272 + m_e * 16 + (ue & 3) * 4;
      floatx4 p0 = *(const floatx4*)&Part[pb];
      floatx4 p1 = *(const floatx4*)&Part[1088 + pb];
      floatx4 p2 = *(const floatx4*)&Part[2176 + pb];
      floatx4 p3 = *(const floatx4*)&Part[3264 + pb];
      const float xg0 = bf16f((unsigned short)(xpcur[0] & 0xffffu));
      const float xg1 = bf16f((unsigned short)(xpcur[0] >> 16));
      const float xg2 = bf16f((unsigned short)(xpcur[1] & 0xffffu));
      const float xg3 = bf16f((unsigned short)(xpcur[1] >> 16));
      const float pi = xg0 + p0[0] + p1[0] + p2[0] + p3[0];
      const float pf = xg1 + p0[1] + p1[1] + p2[1] + p3[1];
      const float pg = xg2 + p0[2] + p1[2] + p2[2] + p3[2];
      const float po = xg3 + p0[3] + p1[3] + p2[3] + p3[3];
      const float gi_ = sigm(pi), gf = sigm(pf), gg = tanh_(pg), go = sigm(po);
      cst = gf * cst + gi_ * gg;
      const float hv = go * tanh_(cst);
      // dual-publish {tag=t+1 | packed hi/lo}: FAST (plain store -> local
      // L2, write-through L1) and SLOW (agent atomic -> LLC). No drains.
      const __bf16 hb = (__bf16)hv;
      const __bf16 lb = (__bf16)(hv - (float)hb);
      const unsigned pk =
          ((unsigned)__builtin_bit_cast(unsigned short, hb) << 16) |
          (unsigned)__builtin_bit_cast(unsigned short, lb);
      const unsigned long long ent =
          ((unsigned long long)(unsigned)(t + 1) << 32) | (unsigned long long)pk;
      *(volatile unsigned long long*)(fpub_base +
                                      (size_t)((t + 1) & 1) * 131072) = ent;
      __hip_atomic_store(spub_base + (size_t)((t + 1) & 1) * 16384, ent,
                         __ATOMIC_RELAXED, __HIP_MEMORY_SCOPE_AGENT);
      // off-path stores: out now, hid captured in a register
      out[((size_t)b_e * 2048 + t) * 512 + u_e] = (t < lenb) ? hv : 0.f;
      if (t == lenb - 1) hcap = hv;
    }
    xpcur = xpnext;
  }
  hid[b_e * 512 + u_e] = hcap;
}

// ---------------------------------------------------------------------------
extern "C" void kernel_launch(void* const* d_in, const int* in_sizes, int n_in,
                              void* d_out, int out_size, void* d_ws, size_t ws_size,
                              hipStream_t stream) {
  const float* x = (const float*)d_in[0];
  const int* lengths = (const int*)d_in[1];
  const float* Wih = (const float*)d_in[2];
  const float* Whh = (const float*)d_in[3];
  const float* bih = (const float*)d_in[4];
  const float* bhh = (const float*)d_in[5];
  float* outf = (float*)d_out;
  char* ws = (char*)d_ws;
  if (ws_size < WS_NEED) return;

  float* biasp = (float*)(ws + BIAS_OFF);
  __bf16* xp = (__bf16*)(ws + XP_OFF);
  unsigned long long* fastR = (unsigned long long*)(ws + FAST_OFF);
  unsigned long long* slowR = (unsigned long long*)(ws + SLOW_OFF);

  prep_kernel<<<64, 256, 0, stream>>>(bih, bhh, lengths, biasp, fastR, outf);
  xproj_gemm<<<32768, 256, 0, stream>>>(x, Wih, biasp, xp);
  // grid 256 = 1 WG per CU (LDS-throttled): block i -> CU i, XCD = i%8.
  // Clubs = blocks ==0/==1 (mod 8); other 192 blocks exit immediately.
  lstm_rec<<<256, 256, 0, stream>>>(Whh, lengths, xp, outf,
                                    outf + HIDDEN_OFF_F, fastR, slowR);
}

// Round 4
// 7091.880 us; speedup vs baseline: 2.6627x; 2.6627x over previous
//
#include <hip/hip_runtime.h>

// ---------------------------------------------------------------------------
// LSTM B=32, S=2048, E=512, H=512 (gates 4H=2048), fp32 in/out.
//   prep_kernel : permuted bias, zero h planes + flags, lengths->floats.
//   xproj_gemm  : xp[t][b][n''] bf16 = x @ W_ih^T + bias (split-bf16 MFMA).
//                 n'' = (u>>2)*16 + (u&3)*4 + g  -> the 4 gate pre-acts of a
//                 (b,u) pair are CONTIGUOUS (one 8B load in the recurrence).
//   lstm_rec    : persistent, 64 WGs x 256 thr = two independent 32-WG clubs
//                 (one per batch half). WG = 16 units x 16 batches. W_hh in
//                 VGPRs (bf16 hi/lo split, 3-term MFMA). Per step:
//                   poll 32 flags (lane-parallel load, no RMW) ->
//                   coalesced 8B agent-atomic staging of packed h -> LDS ->
//                   MFMA (K split over 4 waves) -> LDS reduce ->
//                   elementwise on all 256 threads (1 (b,u) each) ->
//                   h publish (agent atomic) -> vmcnt drain -> flag store ->
//                   out[] store + xp prefetch (both off the critical path).
//
//   R8 (vs verified R4 @7.0ms): STREAMING TRAFFIC MADE NON-POLLUTING.
//   Evidence: R5's poll-heavy variant doubled FETCH_SIZE (660MB->1.19GB) and
//   got SLOWER; R7's nt xp/out hints halved FETCH (->328MB). Theory: the xp
//   read stream (256MB) + out write stream (256MB) evict the tiny hpk/flag
//   lines from LLC, so every poll/staging RT is HBM-class (~900cy) instead
//   of LLC-class (~500cy) and the ~8200cy/step is mostly slow retry rounds.
//   Changes (protocol/numerics byte-identical to R4):
//     * xp loads nontemporal (no allocate), issued at the LOOP TAIL after
//       the flag store -> publish drain no longer waits a fresh prefetch.
//     * out[] stores nontemporal.
//   Exchange medium stays agent-scope atomics: R7 proved plain cross-L2
//   stores are only visible after ~10-20k-cy writeback (2.5x slower).
// ---------------------------------------------------------------------------

typedef __attribute__((ext_vector_type(8))) __bf16 bf16x8;
typedef __attribute__((ext_vector_type(8))) short short8;
typedef __attribute__((ext_vector_type(4))) float floatx4;

// ws layout (bytes)
#define XP_OFF   0ull
#define XP_BYTES (2048ull * 32ull * 2048ull * 2ull)   // 268,435,456
#define HPK_OFF  (XP_OFF + XP_BYTES)                  // 2 bufs x 32x512 dwords
#define HPK_BYTES (2ull * 16384ull * 4ull)
#define BIAS_OFF (HPK_OFF + HPK_BYTES)
#define FLAG_OFF (BIAS_OFF + 8192ull)                 // flags[2][32] dwords
#define WS_NEED  (FLAG_OFF + 256ull)

// d_out layout (fp32): out[32][2048][1][512], lengths[32], hidden[1][32][512]
#define LEN_OFF_F    33554432
#define HIDDEN_OFF_F 33554464

__device__ inline float sigm(float x) { return 1.f / (1.f + __expf(-x)); }
__device__ inline float tanh_(float x) {
  float e = __expf(-2.f * fabsf(x));
  float r = (1.f - e) / (1.f + e);
  return x >= 0.f ? r : -r;
}

__device__ inline void cvt_hilo8(const float* v, bf16x8& hi, bf16x8& lo) {
#pragma unroll
  for (int i = 0; i < 8; ++i) {
    __bf16 h = (__bf16)v[i];
    hi[i] = h;
    lo[i] = (__bf16)(v[i] - (float)h);
  }
}

__device__ inline float bf16f(unsigned short u) {
  union { unsigned u; float f; } c; c.u = ((unsigned)u) << 16; return c.f;
}

// ---------------------------------------------------------------------------
__global__ __launch_bounds__(256) void prep_kernel(
    const float* __restrict__ bih, const float* __restrict__ bhh,
    const int* __restrict__ len, float* __restrict__ biasp,
    unsigned* __restrict__ hpk, unsigned* __restrict__ flags,
    float* __restrict__ outf) {
  const int tid = threadIdx.x;
  for (int i = tid; i < 2048; i += 256) {
    // n'' = ug4*16 + ul*4 + g  ->  W row = g*512 + ug4*4 + ul
    int rowg = (i & 3) * 512 + (i >> 4) * 4 + ((i >> 2) & 3);
    biasp[i] = bih[rowg] + bhh[rowg];
  }
  for (int i = tid; i < 32768; i += 256) hpk[i] = 0u;
  if (tid < 64) flags[tid] = 0u;
  if (tid < 32) outf[LEN_OFF_F + tid] = (float)len[tid];
}

// ---------------------------------------------------------------------------
// xp GEMM: M=65536 (b*2048+s), N=2048 (n''), K=512. Tile 64x64, BK=32.
__global__ __launch_bounds__(256) void xproj_gemm(
    const float* __restrict__ x, const float* __restrict__ Wih,
    const float* __restrict__ biasp, __bf16* __restrict__ xp) {
  __shared__ short Ash[64 * 40], Asl[64 * 40], Bsh[64 * 40], Bsl[64 * 40];
  const int tid = threadIdx.x;
  const int w = tid >> 6, lane = tid & 63, ln = lane & 15, kq = lane >> 4;
  const int ntile = blockIdx.x & 31, mtile = blockIdx.x >> 5;
  const int srow = tid >> 2, sseg = tid & 3;

  const size_t a_base = (size_t)(mtile * 64 + srow) * 512 + sseg * 8;
  const int np_s = ntile * 64 + srow;
  const int rowg = (np_s & 3) * 512 + (np_s >> 4) * 4 + ((np_s >> 2) & 3);
  const size_t b_base = (size_t)rowg * 512 + sseg * 8;

  floatx4 acc[4] = {{0,0,0,0},{0,0,0,0},{0,0,0,0},{0,0,0,0}};

  for (int k0 = 0; k0 < 512; k0 += 32) {
    floatx4 a0 = *(const floatx4*)(x + a_base + k0);
    floatx4 a1 = *(const floatx4*)(x + a_base + k0 + 4);
    floatx4 b0 = *(const floatx4*)(Wih + b_base + k0);
    floatx4 b1 = *(const floatx4*)(Wih + b_base + k0 + 4);
    __syncthreads();
    {
      float va[8] = {a0[0],a0[1],a0[2],a0[3],a1[0],a1[1],a1[2],a1[3]};
      bf16x8 hi, lo; cvt_hilo8(va, hi, lo);
      *(short8*)&Ash[srow * 40 + sseg * 8] = __builtin_bit_cast(short8, hi);
      *(short8*)&Asl[srow * 40 + sseg * 8] = __builtin_bit_cast(short8, lo);
      float vb[8] = {b0[0],b0[1],b0[2],b0[3],b1[0],b1[1],b1[2],b1[3]};
      cvt_hilo8(vb, hi, lo);
      *(short8*)&Bsh[srow * 40 + sseg * 8] = __builtin_bit_cast(short8, hi);
      *(short8*)&Bsl[srow * 40 + sseg * 8] = __builtin_bit_cast(short8, lo);
    }
    __syncthreads();
    bf16x8 ah = __builtin_bit_cast(bf16x8, *(const short8*)&Ash[(16 * w + ln) * 40 + kq * 8]);
    bf16x8 al = __builtin_bit_cast(bf16x8, *(const short8*)&Asl[(16 * w + ln) * 40 + kq * 8]);
#pragma unroll
    for (int nt = 0; nt < 4; ++nt) {
      bf16x8 bh = __builtin_bit_cast(bf16x8, *(const short8*)&Bsh[(nt * 16 + ln) * 40 + kq * 8]);
      bf16x8 bl = __builtin_bit_cast(bf16x8, *(const short8*)&Bsl[(nt * 16 + ln) * 40 + kq * 8]);
      acc[nt] = __builtin_amdgcn_mfma_f32_16x16x32_bf16(ah, bh, acc[nt], 0, 0, 0);
      acc[nt] = __builtin_amdgcn_mfma_f32_16x16x32_bf16(al, bh, acc[nt], 0, 0, 0);
      acc[nt] = __builtin_amdgcn_mfma_f32_16x16x32_bf16(ah, bl, acc[nt], 0, 0, 0);
    }
  }
#pragma unroll
  for (int nt = 0; nt < 4; ++nt) {
    const int npg = ntile * 64 + nt * 16 + ln;
    const float bs = biasp[npg];
#pragma unroll
    for (int r = 0; r < 4; ++r) {
      const int m = mtile * 64 + w * 16 + kq * 4 + r;
      const int s = m & 2047, b = m >> 11;
      xp[(size_t)(s * 32 + b) * 2048 + npg] = (__bf16)(acc[nt][r] + bs);
    }
  }
}

// ---------------------------------------------------------------------------
__global__ __launch_bounds__(256, 1) void lstm_rec(
    const float* __restrict__ Whh, const int* __restrict__ lengths,
    const __bf16* __restrict__ xp, float* __restrict__ out,
    float* __restrict__ hid, unsigned* __restrict__ hpk,
    unsigned* __restrict__ flags) {
  __shared__ short Hh[16 * 512];       // [m][k] bf16 hi, xor-swizzled granules
  __shared__ short Hl[16 * 512];
  __shared__ float Part[4 * 1088];     // [wave][nt(272 pad)][m][n]

  const int tid = threadIdx.x;
  const int w = tid >> 6, lane = tid & 63, ln = lane & 15, kq = lane >> 4;
  const int bh = blockIdx.x >> 5;      // batch half
  const int ug = blockIdx.x & 31;      // 16-unit group
  const int b0 = bh * 16;

  // Persistent W_hh frags. Tile nt, lane ln: g=ln&3, ul=ln>>2,
  // unit = ug*16 + nt*4 + ul, row = g*512 + unit. K-slice of wave w.
  bf16x8 whi[4][4], wlo[4][4];
#pragma unroll
  for (int nt = 0; nt < 4; ++nt) {
    const int rowg = (ln & 3) * 512 + (ug * 4 + nt) * 4 + (ln >> 2);
#pragma unroll
    for (int kc = 0; kc < 4; ++kc) {
      const int k = w * 128 + kc * 32 + kq * 8;
      floatx4 f0 = *(const floatx4*)(Whh + (size_t)rowg * 512 + k);
      floatx4 f1 = *(const floatx4*)(Whh + (size_t)rowg * 512 + k + 4);
      float v[8] = {f0[0],f0[1],f0[2],f0[3],f1[0],f1[1],f1[2],f1[3]};
      cvt_hilo8(v, whi[nt][kc], wlo[nt][kc]);
    }
  }

  // Elementwise ownership: 1 (batch,unit) per thread.
  const int m_e = tid >> 4, ue = tid & 15;
  const int b_e = b0 + m_e, u_e = ug * 16 + ue;
  const int lenb = lengths[b_e];
  float cst = 0.f, hcap = 0.f;

  // xp: this thread's 4 gate pre-acts are 8B contiguous. NONTEMPORAL: pure
  // streaming; keep it from evicting the hot hpk/flag lines (R8 change).
  const __bf16* xpb = xp + (size_t)b_e * 2048 + ug * 64 + (ue >> 2) * 16 + (ue & 3) * 4;
  unsigned long long xpcur =
      __builtin_nontemporal_load((const unsigned long long*)xpb);  // t = 0
  unsigned long long xpnext;

  unsigned* myflag = flags + bh * 32 + ug;
  const unsigned* pollp = flags + bh * 32 + (lane & 31);

  for (int t = 0; t < 2048; ++t) {
    // ---- poll: all 32 producer flags >= t (lane-parallel load, no RMW) ----
    if (w == 0 && t > 0) {
      for (;;) {
        unsigned f = __hip_atomic_load(pollp, __ATOMIC_RELAXED,
                                       __HIP_MEMORY_SCOPE_AGENT);
        if (__ballot(f < (unsigned)t) == 0ull) break;
        __builtin_amdgcn_s_sleep(1);
      }
    }
    __syncthreads();
    // ---- stage packed h: 16 x 8B agent atomics, coalesced 1KB/wave-row ----
    const unsigned* src = hpk + (t & 1) * 16384 + b0 * 512;
    unsigned long long v[16];
#pragma unroll
    for (int k = 0; k < 16; ++k)
      v[k] = __hip_atomic_load(
          (const unsigned long long*)(src + k * 512 + tid * 2),
          __ATOMIC_RELAXED, __HIP_MEMORY_SCOPE_AGENT);
    // ---- unpack hi/lo -> swizzled LDS planes (2-way-free bank pattern) ----
    {
      const int g = tid >> 2;  // 8-unit granule of units (tid*2, tid*2+1)
#pragma unroll
      for (int k = 0; k < 16; ++k) {
        const unsigned w0 = (unsigned)v[k], w1 = (unsigned)(v[k] >> 32);
        const int d = k * 512 + ((g ^ (k & 7)) * 8) + (tid & 3) * 2;
        *(unsigned*)&Hh[d] = (w0 >> 16) | (w1 & 0xffff0000u);
        *(unsigned*)&Hl[d] = (w0 & 0xffffu) | (w1 << 16);
      }
    }
    __syncthreads();
    // ---- MFMA: M=16 batches x N=16 gate-rows x 4 tiles, wave K-slice ----
    floatx4 acc[4] = {{0,0,0,0},{0,0,0,0},{0,0,0,0},{0,0,0,0}};
#pragma unroll
    for (int kc = 0; kc < 4; ++kc) {
      const int g = w * 16 + kc * 4 + kq;
      const int d = ln * 512 + ((g ^ (ln & 7)) * 8);
      bf16x8 ah = __builtin_bit_cast(bf16x8, *(const short8*)&Hh[d]);
      bf16x8 al = __builtin_bit_cast(bf16x8, *(const short8*)&Hl[d]);
#pragma unroll
      for (int nt = 0; nt < 4; ++nt) {
        acc[nt] = __builtin_amdgcn_mfma_f32_16x16x32_bf16(ah, whi[nt][kc], acc[nt], 0, 0, 0);
        acc[nt] = __builtin_amdgcn_mfma_f32_16x16x32_bf16(al, whi[nt][kc], acc[nt], 0, 0, 0);
        acc[nt] = __builtin_amdgcn_mfma_f32_16x16x32_bf16(ah, wlo[nt][kc], acc[nt], 0, 0, 0);
      }
    }
#pragma unroll
    for (int nt = 0; nt < 4; ++nt)
#pragma unroll
      for (int r4 = 0; r4 < 4; ++r4)
        Part[w * 1088 + nt * 272 + (kq * 4 + r4) * 16 + ln] = acc[nt][r4];
    __syncthreads();
    // ---- reduce + gates + state (all 256 threads, one (b,u) each) ----
    {
      const int pb = (ue >> 2) * 272 + m_e * 16 + (ue & 3) * 4;
      floatx4 p0 = *(const floatx4*)&Part[pb];
      floatx4 p1 = *(const floatx4*)&Part[1088 + pb];
      floatx4 p2 = *(const floatx4*)&Part[2176 + pb];
      floatx4 p3 = *(const floatx4*)&Part[3264 + pb];
      const float xg0 = bf16f((unsigned short)(xpcur & 0xffffu));
      const float xg1 = bf16f((unsigned short)((xpcur >> 16) & 0xffffu));
      const float xg2 = bf16f((unsigned short)((xpcur >> 32) & 0xffffu));
      const float xg3 = bf16f((unsigned short)(xpcur >> 48));
      const float pi = xg0 + p0[0] + p1[0] + p2[0] + p3[0];
      const float pf = xg1 + p0[1] + p1[1] + p2[1] + p3[1];
      const float pg = xg2 + p0[2] + p1[2] + p2[2] + p3[2];
      const float po = xg3 + p0[3] + p1[3] + p2[3] + p3[3];
      const float gi_ = sigm(pi), gf = sigm(pf), gg = tanh_(pg), go = sigm(po);
      cst = gf * cst + gi_ * gg;
      const float hv = go * tanh_(cst);
      // publish h (packed hi/lo) to the other buffer
      const __bf16 hb = (__bf16)hv;
      const __bf16 lb = (__bf16)(hv - (float)hb);
      const unsigned pk =
          ((unsigned)__builtin_bit_cast(unsigned short, hb) << 16) |
          (unsigned)__builtin_bit_cast(unsigned short, lb);
      __hip_atomic_store(hpk + ((t + 1) & 1) * 16384 + b_e * 512 + u_e, pk,
                         __ATOMIC_RELAXED, __HIP_MEMORY_SCOPE_AGENT);
      asm volatile("s_waitcnt vmcnt(0)" ::: "memory");  // h store drained
      __syncthreads();                                  // ...by ALL waves
      if (tid == 0)
        __hip_atomic_store(myflag, (unsigned)(t + 1), __ATOMIC_RELAXED,
                           __HIP_MEMORY_SCOPE_AGENT);
      // off-path: out store (nontemporal), then xp prefetch for t+1 (issued
      // AFTER the drain so the drain never waits a fresh prefetch; it has
      // the whole next poll window to complete).
      __builtin_nontemporal_store((t < lenb) ? hv : 0.f,
                                  &out[((size_t)b_e * 2048 + t) * 512 + u_e]);
      if (t == lenb - 1) hcap = hv;
    }
    {
      const int tn = (t + 1 < 2048) ? t + 1 : 2047;
      xpnext = __builtin_nontemporal_load(
          (const unsigned long long*)(xpb + (size_t)tn * 65536));
    }
    xpcur = xpnext;
  }
  hid[b_e * 512 + u_e] = hcap;
}

// ---------------------------------------------------------------------------
extern "C" void kernel_launch(void* const* d_in, const int* in_sizes, int n_in,
                              void* d_out, int out_size, void* d_ws, size_t ws_size,
                              hipStream_t stream) {
  const float* x = (const float*)d_in[0];
  const int* lengths = (const int*)d_in[1];
  const float* Wih = (const float*)d_in[2];
  const float* Whh = (const float*)d_in[3];
  const float* bih = (const float*)d_in[4];
  const float* bhh = (const float*)d_in[5];
  float* outf = (float*)d_out;
  char* ws = (char*)d_ws;
  if (ws_size < WS_NEED) return;

  float* biasp = (float*)(ws + BIAS_OFF);
  __bf16* xp = (__bf16*)(ws + XP_OFF);
  unsigned* hpk = (unsigned*)(ws + HPK_OFF);
  unsigned* flags = (unsigned*)(ws + FLAG_OFF);

  prep_kernel<<<1, 256, 0, stream>>>(bih, bhh, lengths, biasp, hpk, flags, outf);
  xproj_gemm<<<32768, 256, 0, stream>>>(x, Wih, biasp, xp);
  lstm_rec<<<64, 256, 0, stream>>>(Whh, lengths, xp, outf,
                                   outf + HIDDEN_OFF_F, hpk, flags);
}